// Round 13
// baseline (464.837 us; speedup 1.0000x reference)
//
#include <hip/hip_runtime.h>
#include <hip/hip_bf16.h>
#include <stdint.h>

#define T_TOK 2048
#define HID   4096
#define NH    32
#define NKV   8
#define HD    128
#define NQKV  6144
#define QSCALE 0.08838834764831845f  // 1/sqrt(128)

typedef __bf16 bf16x8 __attribute__((ext_vector_type(8)));
typedef float  f32x4  __attribute__((ext_vector_type(4)));
typedef unsigned short su8 __attribute__((ext_vector_type(8)));
typedef unsigned short su4 __attribute__((ext_vector_type(4)));

__device__ __forceinline__ unsigned short f2bf(float f) {
  union { float f; unsigned u; } x; x.f = f;
  unsigned r = x.u + 0x7FFFu + ((x.u >> 16) & 1u);
  return (unsigned short)(r >> 16);
}
__device__ __forceinline__ float bf2f(unsigned short u) {
  union { unsigned u; float f; } x; x.u = (unsigned)u << 16; return x.f;
}

__device__ __forceinline__ f32x4 mfma16(su8 a, su8 b, f32x4 c) {
  return __builtin_amdgcn_mfma_f32_16x16x32_bf16(
      __builtin_bit_cast(bf16x8, a), __builtin_bit_cast(bf16x8, b), c, 0, 0, 0);
}

#define GLOAD_LDS16(gp, lp)                                                     \
  __builtin_amdgcn_global_load_lds(                                             \
      (const __attribute__((address_space(1))) void*)(gp),                      \
      (__attribute__((address_space(3))) void*)(lp), 16, 0, 0)

// ---------------------------------------------------------------------------
// Routing: compact token indices per expert (vision / language)
// ---------------------------------------------------------------------------
__launch_bounds__(256)
__global__ void route_kernel(const int* __restrict__ vm,
                             int* __restrict__ idx_v, int* __restrict__ idx_l,
                             int* __restrict__ cnts) {
  __shared__ int sv[256], sl[256];
  int tid = threadIdx.x;
  int loc[8]; int lv = 0;
  #pragma unroll
  for (int i = 0; i < 8; i++) { loc[i] = (vm[tid * 8 + i] != 0); lv += loc[i]; }
  int ll = 8 - lv;
  sv[tid] = lv; sl[tid] = ll;
  __syncthreads();
  for (int off = 1; off < 256; off <<= 1) {
    int a = (tid >= off) ? sv[tid - off] : 0;
    int b = (tid >= off) ? sl[tid - off] : 0;
    __syncthreads();
    sv[tid] += a; sl[tid] += b;
    __syncthreads();
  }
  int bv = sv[tid] - lv, bl = sl[tid] - ll;
  #pragma unroll
  for (int i = 0; i < 8; i++) {
    int t = tid * 8 + i;
    if (loc[i]) idx_v[bv++] = t; else idx_l[bl++] = t;
  }
  if (tid == 255) { cnts[0] = sv[255]; cnts[1] = sl[255]; }
}

// ---------------------------------------------------------------------------
// Transpose-convert both experts' weights: W[k][n] f32 -> Wt[n][k] bf16
// ---------------------------------------------------------------------------
__launch_bounds__(256)
__global__ void convert_wt2(const float* __restrict__ W0, const float* __restrict__ W1,
                            unsigned short* __restrict__ Wt0, unsigned short* __restrict__ Wt1,
                            int N) {
  const float* W = blockIdx.z ? W1 : W0;
  unsigned short* Wt = blockIdx.z ? Wt1 : Wt0;
  __shared__ float tile[64][65];
  int n0 = blockIdx.x * 64, k0 = blockIdx.y * 64;
  int tid = threadIdx.x;
  int tr = tid >> 4, tc4 = (tid & 15) * 4;
  #pragma unroll
  for (int p = 0; p < 4; p++) {
    int k = p * 16 + tr;
    float4 v = *(const float4*)(W + (size_t)(k0 + k) * N + n0 + tc4);
    tile[tc4 + 0][k] = v.x; tile[tc4 + 1][k] = v.y;
    tile[tc4 + 2][k] = v.z; tile[tc4 + 3][k] = v.w;
  }
  __syncthreads();
  int n = tid >> 2, kc = (tid & 3) * 16;
  unsigned short obuf[16];
  #pragma unroll
  for (int j = 0; j < 16; j++) obuf[j] = f2bf(tile[n][kc + j]);
  su8* dst = (su8*)(Wt + (size_t)(n0 + n) * 4096 + k0 + kc);
  dst[0] = *(su8*)&obuf[0];
  dst[1] = *(su8*)&obuf[8];
}

// f32 -> bf16 elementwise (8 elems/thread)
__launch_bounds__(256)
__global__ void convert_x(const float* __restrict__ x,
                          unsigned short* __restrict__ xb, int n8) {
  int i = blockIdx.x * 256 + threadIdx.x;
  if (i < n8) {
    float4 a = ((const float4*)x)[i * 2], b = ((const float4*)x)[i * 2 + 1];
    su8 u = { f2bf(a.x), f2bf(a.y), f2bf(a.z), f2bf(a.w),
              f2bf(b.x), f2bf(b.y), f2bf(b.z), f2bf(b.w) };
    ((su8*)xb)[i] = u;
  }
}

// ---------------------------------------------------------------------------
// bf16 gathered GEMM, double-buffered, COUNTED vmcnt, split-MFMA schedule:
//   iter t: vmcnt(8); bar;
//           ds_read 16 frags; MFMA s0 (compiler interleaves w/ s1-read latency);
//           lgkm(0); bar; STAGE(buf t&1, t+2); MFMA s1
// Same sync points as r9/r12 (WAR: all frags in regs + barrier before STAGE);
// the two 16-MFMA halves now cover the ds_read tail and the STAGE issue.
// BM=128 BN=128 BK=64, 4 waves (2x2), wave tile 64x64, LDS 2x32KB = 64KB.
// global_load_lds linear dest + inverse-swizzled global source; reads use
// byte ^= ((row&7)<<4) (G4 recipe) -> 0 bank conflicts (verified r2/r4/r8/r9).
// ---------------------------------------------------------------------------
template <bool OBF16>
__launch_bounds__(256)
__global__ void gemm_bf16(const unsigned short* __restrict__ A,   // [2048][4096]
                          const unsigned short* __restrict__ Wv,  // [N][4096]
                          const unsigned short* __restrict__ Wl,
                          const int* __restrict__ idx_v, const int* __restrict__ idx_l,
                          const int* __restrict__ cnts,
                          void* __restrict__ out, int N) {
  int e = blockIdx.z;
  const unsigned short* Wt = e ? Wl : Wv;
  const int* gidx = e ? idx_l : idx_v;
  int cnt = cnts[e];
  int m0 = blockIdx.y * 128;
  if (cnt == 0 || m0 >= cnt) return;
  // T1: XCD-aware n-tile swizzle (bijective when gridDim.x % 8 == 0)
  int nx = gridDim.x;
  int bx = blockIdx.x;
  int bxs = (nx % 8 == 0) ? ((bx & 7) * (nx >> 3) + (bx >> 3)) : bx;
  int n0 = bxs * 128;

  __shared__ __align__(16) unsigned short a_lds[2][128 * 64];
  __shared__ __align__(16) unsigned short b_lds[2][128 * 64];

  int tid = threadIdx.x;
  int lane = tid & 63;
  int w = tid >> 6;
  int lg = lane >> 4, lr = lane & 15;
  int wm = w >> 1, wn = w & 1;

  // per-lane staging source bases (row = chunk*8 + (lane>>3), swizzled col)
  int srow = lane >> 3;
  int scolb = ((lane & 7) ^ srow) << 4;
  const char* a_src[4];
  const char* b_src[4];
  #pragma unroll
  for (int j = 0; j < 4; j++) {
    int c = w * 4 + j;
    int r = c * 8 + srow;
    int gr = gidx[min(m0 + r, cnt - 1)];
    a_src[j] = (const char*)(A + (size_t)gr * 4096) + scolb;
    b_src[j] = (const char*)(Wt + (size_t)(n0 + r) * 4096) + scolb;
  }

  f32x4 acc[4][4];
  #pragma unroll
  for (int fm = 0; fm < 4; fm++)
    #pragma unroll
    for (int fn = 0; fn < 4; fn++)
      acc[fm][fn] = (f32x4){0.f, 0.f, 0.f, 0.f};

  auto STAGE = [&](int buf, int kt) {
    size_t kb = (size_t)kt * 128;  // 64 k-elems * 2B
    #pragma unroll
    for (int j = 0; j < 4; j++) {
      int c = w * 4 + j;
      GLOAD_LDS16(a_src[j] + kb, (char*)a_lds[buf] + c * 1024);
      GLOAD_LDS16(b_src[j] + kb, (char*)b_lds[buf] + c * 1024);
    }
  };

  // prologue: two tiles in flight
  STAGE(0, 0);
  STAGE(1, 1);

  for (int t = 0; t < 64; ++t) {
    if (t < 63) { asm volatile("s_waitcnt vmcnt(8)" ::: "memory"); }
    else        { asm volatile("s_waitcnt vmcnt(0)" ::: "memory"); }
    __builtin_amdgcn_s_barrier();
    asm volatile("" ::: "memory");

    // ds_read ALL fragments of buf[t&1] into registers
    const char* la = (const char*)a_lds[t & 1];
    const char* lb = (const char*)b_lds[t & 1];
    su8 af[2][4], bfr[2][4];
    #pragma unroll
    for (int s = 0; s < 2; s++) {
      int colb = s * 64 + lg * 16;
      #pragma unroll
      for (int fm = 0; fm < 4; fm++) {
        int r = wm * 64 + fm * 16 + lr;
        af[s][fm] = *(const su8*)(la + r * 128 + (colb ^ ((r & 7) << 4)));
      }
      #pragma unroll
      for (int fn = 0; fn < 4; fn++) {
        int r = wn * 64 + fn * 16 + lr;
        bfr[s][fn] = *(const su8*)(lb + r * 128 + (colb ^ ((r & 7) << 4)));
      }
    }
    // first MFMA half: compiler's fine-grained lgkmcnt starts it once the
    // s=0 reads land; its matrix-pipe work covers the s=1 reads' latency.
    __builtin_amdgcn_s_setprio(1);
    #pragma unroll
    for (int fm = 0; fm < 4; fm++)
      #pragma unroll
      for (int fn = 0; fn < 4; fn++)
        acc[fm][fn] = mfma16(af[0][fm], bfr[0][fn], acc[fm][fn]);
    __builtin_amdgcn_s_setprio(0);
    __builtin_amdgcn_sched_barrier(0);
    // all 16 reads done + block-wide barrier -> buf is free for STAGE
    asm volatile("s_waitcnt lgkmcnt(0)" ::: "memory");
    __builtin_amdgcn_sched_barrier(0);
    __builtin_amdgcn_s_barrier();
    asm volatile("" ::: "memory");

    // issue next-next tile's loads, second MFMA half covers the issue
    if (t + 2 < 64) STAGE(t & 1, t + 2);
    __builtin_amdgcn_s_setprio(1);
    #pragma unroll
    for (int fm = 0; fm < 4; fm++)
      #pragma unroll
      for (int fn = 0; fn < 4; fn++)
        acc[fm][fn] = mfma16(af[1][fm], bfr[1][fn], acc[fm][fn]);
    __builtin_amdgcn_s_setprio(0);
  }

  // epilogue: C/D layout row=(lane>>4)*4+i, col=lane&15
  #pragma unroll
  for (int fm = 0; fm < 4; fm++) {
    #pragma unroll
    for (int i = 0; i < 4; i++) {
      int r = wm * 64 + fm * 16 + lg * 4 + i;
      if (m0 + r < cnt) {
        int grow = gidx[m0 + r];
        #pragma unroll
        for (int fn = 0; fn < 4; fn++) {
          size_t off = (size_t)grow * N + n0 + wn * 64 + fn * 16 + lr;
          if (OBF16) ((unsigned short*)out)[off] = f2bf(acc[fm][fn][i]);
          else       ((float*)out)[off] = acc[fm][fn][i];
        }
      }
    }
  }
}

// ---------------------------------------------------------------------------
// OLD f32-staging gathered GEMM (fallback if workspace is small)
// ---------------------------------------------------------------------------
__launch_bounds__(256)
__global__ void gemm_gather(const float* __restrict__ X,
                            const float* __restrict__ Wv, const float* __restrict__ Wl,
                            const int* __restrict__ idx_v, const int* __restrict__ idx_l,
                            const int* __restrict__ cnts,
                            float* __restrict__ out, int N) {
  int e = blockIdx.z;
  const float* W = e ? Wl : Wv;
  const int* gidx = e ? idx_l : idx_v;
  int cnt = cnts[e];
  int m0 = blockIdx.y * 128;
  if (cnt == 0 || m0 >= cnt) return;
  int n0 = blockIdx.x * 64;

  __shared__ __align__(16) unsigned short a_lds[128][72];
  __shared__ __align__(16) unsigned short b_lds[64][72];

  int tid = threadIdx.x;
  int lane = tid & 63;
  int w = tid >> 6;
  int lg = lane >> 4, lr = lane & 15;
  int wm = w >> 1, wn = w & 1;

  int ar = tid >> 1;
  int akc = (tid & 1) * 32;
  const float* Arow = X + (size_t)gidx[min(m0 + ar, cnt - 1)] * HID;
  int bk = (tid >> 4) * 4;
  int bj = (tid & 15) * 4;

  f32x4 acc[4][2];
  #pragma unroll
  for (int fm = 0; fm < 4; fm++)
    #pragma unroll
    for (int fn = 0; fn < 2; fn++)
      acc[fm][fn] = (f32x4){0.f, 0.f, 0.f, 0.f};

  for (int k0 = 0; k0 < HID; k0 += 64) {
    {
      const float4* src = (const float4*)(Arow + k0 + akc);
      float4 f[8];
      #pragma unroll
      for (int i = 0; i < 8; i++) f[i] = src[i];
      #pragma unroll
      for (int i = 0; i < 4; i++) {
        float4 a0 = f[2 * i], a1 = f[2 * i + 1];
        su8 u = { f2bf(a0.x), f2bf(a0.y), f2bf(a0.z), f2bf(a0.w),
                  f2bf(a1.x), f2bf(a1.y), f2bf(a1.z), f2bf(a1.w) };
        *(su8*)&a_lds[ar][akc + i * 8] = u;
      }
    }
    {
      const float* Wp = W + (size_t)(k0 + bk) * N + n0 + bj;
      float4 r0 = *(const float4*)(Wp);
      float4 r1 = *(const float4*)(Wp + N);
      float4 r2 = *(const float4*)(Wp + 2 * (size_t)N);
      float4 r3 = *(const float4*)(Wp + 3 * (size_t)N);
      su4 c0 = { f2bf(r0.x), f2bf(r1.x), f2bf(r2.x), f2bf(r3.x) };
      su4 c1 = { f2bf(r0.y), f2bf(r1.y), f2bf(r2.y), f2bf(r3.y) };
      su4 c2 = { f2bf(r0.z), f2bf(r1.z), f2bf(r2.z), f2bf(r3.z) };
      su4 c3 = { f2bf(r0.w), f2bf(r1.w), f2bf(r2.w), f2bf(r3.w) };
      *(su4*)&b_lds[bj + 0][bk] = c0;
      *(su4*)&b_lds[bj + 1][bk] = c1;
      *(su4*)&b_lds[bj + 2][bk] = c2;
      *(su4*)&b_lds[bj + 3][bk] = c3;
    }
    __syncthreads();
    #pragma unroll
    for (int s = 0; s < 64; s += 32) {
      su8 af[4], bfr[2];
      #pragma unroll
      for (int fm = 0; fm < 4; fm++)
        af[fm] = *(const su8*)&a_lds[wm * 64 + fm * 16 + lr][s + lg * 8];
      #pragma unroll
      for (int fn = 0; fn < 2; fn++)
        bfr[fn] = *(const su8*)&b_lds[wn * 32 + fn * 16 + lr][s + lg * 8];
      #pragma unroll
      for (int fm = 0; fm < 4; fm++)
        #pragma unroll
        for (int fn = 0; fn < 2; fn++)
          acc[fm][fn] = mfma16(af[fm], bfr[fn], acc[fm][fn]);
    }
    __syncthreads();
  }
  #pragma unroll
  for (int fm = 0; fm < 4; fm++) {
    #pragma unroll
    for (int i = 0; i < 4; i++) {
      int r = wm * 64 + fm * 16 + lg * 4 + i;
      if (m0 + r < cnt) {
        int grow = gidx[m0 + r];
        #pragma unroll
        for (int fn = 0; fn < 2; fn++)
          out[(size_t)grow * N + n0 + wn * 32 + fn * 16 + lr] = acc[fm][fn][i];
      }
    }
  }
}

// ---------------------------------------------------------------------------
// RoPE + cache scatter (bf16 qkv input, vectorized)
// ---------------------------------------------------------------------------
__launch_bounds__(256)
__global__ void rope_scatter_bf(const unsigned short* __restrict__ qkv,
                                const int* __restrict__ pos_ids,
                                const int* __restrict__ seq_ids,
                                const int* __restrict__ block_offsets, int max_blocks,
                                const float* __restrict__ inv_freq,
                                unsigned short* __restrict__ q_ws,
                                unsigned short* __restrict__ k_ws,
                                unsigned short* __restrict__ v_ws,
                                float* __restrict__ kc_out, float* __restrict__ vc_out) {
  int t = blockIdx.x;
  int tid = threadIdx.x;
  __shared__ float cs[64], sn[64];
  int pos = pos_ids[t];
  if (tid < 64) {
    float f = (float)pos * inv_freq[tid];
    float s, c;
    sincosf(f, &s, &c);
    cs[tid] = c; sn[tid] = s;
  }
  __syncthreads();
  const unsigned short* row = qkv + (size_t)t * NQKV;
  #pragma unroll
  for (int it = 0; it < 2; it++) {
    int chunk = it * 256 + tid;
    int hh = chunk >> 4;
    int d0 = (chunk & 15) * 8;
    int lo = (d0 < 64);
    int j0 = lo ? d0 : d0 - 64;
    su8 x  = *(const su8*)(row + hh * 128 + d0);
    su8 xp = *(const su8*)(row + hh * 128 + (lo ? d0 + 64 : d0 - 64));
    su8 o;
    #pragma unroll
    for (int jj = 0; jj < 8; jj++) {
      float c = cs[j0 + jj], s = sn[j0 + jj];
      float xv = bf2f(x[jj]), pv = bf2f(xp[jj]);
      float val = lo ? (xv * c - pv * s) : (xv * c + pv * s);
      o[jj] = f2bf(val * QSCALE);
    }
    *(su8*)(q_ws + ((size_t)hh * T_TOK + t) * HD + d0) = o;
  }
  int seq = seq_ids[t];
  int blk = block_offsets[seq * max_blocks + (pos >> 6)];
  int slot = pos & 63;
  int chunk = tid & 127;
  int kvh = chunk >> 4;
  int d0 = (chunk & 15) * 8;
  if (tid < 128) {
    const unsigned short* kr = row + HID;
    int lo = (d0 < 64);
    int j0 = lo ? d0 : d0 - 64;
    su8 x  = *(const su8*)(kr + kvh * 128 + d0);
    su8 xp = *(const su8*)(kr + kvh * 128 + (lo ? d0 + 64 : d0 - 64));
    su8 o;
    float of[8];
    #pragma unroll
    for (int jj = 0; jj < 8; jj++) {
      float c = cs[j0 + jj], s = sn[j0 + jj];
      float xv = bf2f(x[jj]), pv = bf2f(xp[jj]);
      float val = lo ? (xv * c - pv * s) : (xv * c + pv * s);
      of[jj] = val;
      o[jj] = f2bf(val);
    }
    *(su8*)(k_ws + ((size_t)kvh * T_TOK + t) * HD + d0) = o;
    float* kc = kc_out + (((size_t)blk * 64 + slot) * NKV + kvh) * HD + d0;
    *(float4*)kc       = (float4){of[0], of[1], of[2], of[3]};
    *(float4*)(kc + 4) = (float4){of[4], of[5], of[6], of[7]};
  } else {
    const unsigned short* vr = row + HID + NKV * HD;
    su8 x = *(const su8*)(vr + kvh * 128 + d0);
    *(su8*)(v_ws + ((size_t)kvh * T_TOK + t) * HD + d0) = x;
    float* vc = vc_out + (((size_t)blk * 64 + slot) * NKV + kvh) * HD + d0;
    *(float4*)vc       = (float4){bf2f(x[0]), bf2f(x[1]), bf2f(x[2]), bf2f(x[3])};
    *(float4*)(vc + 4) = (float4){bf2f(x[4]), bf2f(x[5]), bf2f(x[6]), bf2f(x[7])};
  }
}

// ---------------------------------------------------------------------------
// RoPE + cache scatter (f32 qkv input, fallback path)
// ---------------------------------------------------------------------------
__launch_bounds__(256)
__global__ void rope_scatter(const float* __restrict__ qkv,
                             const int* __restrict__ pos_ids,
                             const int* __restrict__ seq_ids,
                             const int* __restrict__ block_offsets, int max_blocks,
                             const float* __restrict__ inv_freq,
                             unsigned short* __restrict__ q_ws,
                             unsigned short* __restrict__ k_ws,
                             unsigned short* __restrict__ v_ws,
                             float* __restrict__ kc_out, float* __restrict__ vc_out) {
  int t = blockIdx.x;
  int tid = threadIdx.x;
  __shared__ float cs[64], sn[64];
  int pos = pos_ids[t];
  if (tid < 64) {
    float f = (float)pos * inv_freq[tid];
    float s, c;
    sincosf(f, &s, &c);
    cs[tid] = c; sn[tid] = s;
  }
  __syncthreads();
  const float* row = qkv + (size_t)t * NQKV;
  #pragma unroll 4
  for (int it = 0; it < 16; it++) {
    int idx = it * 256 + tid;
    int hh = idx >> 7, d = idx & 127;
    float val;
    if (d < 64) val = row[hh * 128 + d] * cs[d] - row[hh * 128 + d + 64] * sn[d];
    else { int j = d - 64; val = row[hh * 128 + d] * cs[j] + row[hh * 128 + j] * sn[j]; }
    q_ws[((size_t)hh * T_TOK + t) * HD + d] = f2bf(val * QSCALE);
  }
  int seq = seq_ids[t];
  int blk = block_offsets[seq * max_blocks + (pos >> 6)];
  int slot = pos & 63;
  #pragma unroll
  for (int it = 0; it < 4; it++) {
    int idx = it * 256 + tid;
    int kvh = idx >> 7, d = idx & 127;
    const float* kr = row + HID;
    float val;
    if (d < 64) val = kr[kvh * 128 + d] * cs[d] - kr[kvh * 128 + d + 64] * sn[d];
    else { int j = d - 64; val = kr[kvh * 128 + d] * cs[j] + kr[kvh * 128 + j] * sn[j]; }
    kc_out[(((size_t)blk * 64 + slot) * NKV + kvh) * HD + d] = val;
    k_ws[((size_t)kvh * T_TOK + t) * HD + d] = f2bf(val);
  }
  #pragma unroll
  for (int it = 0; it < 4; it++) {
    int idx = it * 256 + tid;
    int kvh = idx >> 7, d = idx & 127;
    float val = row[HID + NKV * HD + idx];
    vc_out[(((size_t)blk * 64 + slot) * NKV + kvh) * HD + d] = val;
    v_ws[((size_t)kvh * T_TOK + t) * HD + d] = f2bf(val);
  }
}

// ---------------------------------------------------------------------------
// Flash attention, K/V double-buffered pipeline (r12, measured neutral-good):
//   iter kb: issue K-dma(kb+1) + V-reg-loads(kb+1); compute(kb);
//            vmcnt(0); ds_write V(kb+1); barrier
// ---------------------------------------------------------------------------
template <bool BF16OUT>
__launch_bounds__(256)
__global__ void attn_kernel(const unsigned short* __restrict__ q_ws,
                            const unsigned short* __restrict__ k_ws,
                            const unsigned short* __restrict__ v_ws,
                            const int* __restrict__ pos_ids,
                            void* __restrict__ ctx) {
  int qt = blockIdx.x;
  int h = blockIdx.y;
  int kvh = h >> 2;
  int t0 = qt * 64;

  __shared__ __align__(16) unsigned short k_lds[2][64 * 128];
  __shared__ __align__(16) unsigned short v_lds[2][128][72];
  __shared__ __align__(16) unsigned short p_lds[4][16][72];
  unsigned short* q_lds = &v_lds[1][0][0];

  int tid = threadIdx.x;
  int lane = tid & 63;
  int w = tid >> 6;
  int lg = lane >> 4, lr = lane & 15;

  int seq_start = t0 - pos_ids[t0];
  int nkb = (t0 - seq_start) / 64 + 1;

  const char* kbase = (const char*)(k_ws + (size_t)kvh * T_TOK * HD);
  int ksrc_off[4];
  #pragma unroll
  for (int j = 0; j < 4; j++) {
    int c = w * 4 + j;
    int r = c * 4 + (lane >> 4);
    ksrc_off[j] = r * 256 + (((lane & 15) ^ (r & 7)) << 4);
  }
  auto K_STAGE = [&](int buf, int kt0) {
    const char* src = kbase + (size_t)kt0 * 256;
    #pragma unroll
    for (int j = 0; j < 4; j++) {
      int c = w * 4 + j;
      GLOAD_LDS16(src + ksrc_off[j], (char*)k_lds[buf] + c * 1024 + (lane & 63) * 16);
    }
  };
  int vd0 = (tid & 31) * 4, vkey0 = (tid >> 5) * 8;
  su4 vv[8];
  auto V_LOAD = [&](int kt0) {
    #pragma unroll
    for (int r = 0; r < 8; r++)
      vv[r] = *(const su4*)(v_ws + ((size_t)kvh * T_TOK + kt0 + vkey0 + r) * HD + vd0);
  };
  auto V_WRITE = [&](int buf) {
    #pragma unroll
    for (int dd = 0; dd < 4; dd++) {
      su8 u = { vv[0][dd], vv[1][dd], vv[2][dd], vv[3][dd],
                vv[4][dd], vv[5][dd], vv[6][dd], vv[7][dd] };
      *(su8*)&v_lds[buf][vd0 + dd][vkey0] = u;
    }
  };

  {
    int r = tid >> 2, dc = (tid & 3) * 32;
    const su8* src = (const su8*)(q_ws + ((size_t)h * T_TOK + t0 + r) * HD + dc);
    #pragma unroll
    for (int i = 0; i < 4; i++) *(su8*)&q_lds[r * 136 + dc + i * 8] = src[i];
  }
  K_STAGE(0, seq_start);
  V_LOAD(seq_start);
  __syncthreads();
  su8 qf[4];
  #pragma unroll
  for (int s = 0; s < 4; s++)
    qf[s] = *(const su8*)&q_lds[(w * 16 + lr) * 136 + s * 32 + lg * 8];
  asm volatile("s_waitcnt lgkmcnt(0)" ::: "memory");
  __builtin_amdgcn_sched_barrier(0);
  __builtin_amdgcn_s_barrier();
  asm volatile("s_waitcnt vmcnt(0)" ::: "memory");
  V_WRITE(0);
  asm volatile("" ::: "memory");
  __syncthreads();

  f32x4 O[8];
  #pragma unroll
  for (int fd = 0; fd < 8; fd++) O[fd] = (f32x4){0.f, 0.f, 0.f, 0.f};
  float m_i[4] = { -1e30f, -1e30f, -1e30f, -1e30f };
  float l_i[4] = { 0.f, 0.f, 0.f, 0.f };

  for (int kb = 0; kb < nkb; kb++) {
    int cur = kb & 1, nxt = cur ^ 1;
    int kt0 = seq_start + kb * 64;
    if (kb + 1 < nkb) {
      K_STAGE(nxt, kt0 + 64);
      V_LOAD(kt0 + 64);
    }

    const char* kl = (const char*)k_lds[cur];
    f32x4 S[4];
    #pragma unroll
    for (int f = 0; f < 4; f++) S[f] = (f32x4){0.f, 0.f, 0.f, 0.f};
    __builtin_amdgcn_s_setprio(1);
    #pragma unroll
    for (int f = 0; f < 4; f++) {
      int r = f * 16 + lr;
      #pragma unroll
      for (int s = 0; s < 4; s++) {
        su8 kf = *(const su8*)(kl + r * 256 + ((s * 64 + lg * 16) ^ ((r & 7) << 4)));
        S[f] = mfma16(qf[s], kf, S[f]);
      }
    }
    __builtin_amdgcn_s_setprio(0);
    if (kt0 == t0) {
      #pragma unroll
      for (int f = 0; f < 4; f++)
        #pragma unroll
        for (int i = 0; i < 4; i++)
          if (f * 16 + lr > w * 16 + lg * 4 + i) S[f][i] = -1e30f;
    }
    float mnew[4], alpha[4];
    #pragma unroll
    for (int i = 0; i < 4; i++) {
      float mx = fmaxf(fmaxf(S[0][i], S[1][i]), fmaxf(S[2][i], S[3][i]));
      #pragma unroll
      for (int off = 8; off > 0; off >>= 1) mx = fmaxf(mx, __shfl_xor(mx, off, 16));
      mnew[i] = fmaxf(m_i[i], mx);
      alpha[i] = __expf(m_i[i] - mnew[i]);
      m_i[i] = mnew[i];
    }
    float rs[4] = { 0.f, 0.f, 0.f, 0.f };
    #pragma unroll
    for (int f = 0; f < 4; f++)
      #pragma unroll
      for (int i = 0; i < 4; i++) {
        float p = __expf(S[f][i] - mnew[i]);
        S[f][i] = p;
        rs[i] += p;
      }
    #pragma unroll
    for (int i = 0; i < 4; i++) {
      #pragma unroll
      for (int off = 8; off > 0; off >>= 1) rs[i] += __shfl_xor(rs[i], off, 16);
      l_i[i] = l_i[i] * alpha[i] + rs[i];
    }
    #pragma unroll
    for (int f = 0; f < 4; f++)
      #pragma unroll
      for (int i = 0; i < 4; i++)
        p_lds[w][lg * 4 + i][f * 16 + lr] = f2bf(S[f][i]);
    #pragma unroll
    for (int fd = 0; fd < 8; fd++)
      #pragma unroll
      for (int i = 0; i < 4; i++)
        O[fd][i] *= alpha[i];
    __builtin_amdgcn_s_setprio(1);
    #pragma unroll
    for (int kk = 0; kk < 2; kk++) {
      su8 pf = *(const su8*)&p_lds[w][lr][kk * 32 + lg * 8];
      #pragma unroll
      for (int fd = 0; fd < 8; fd++) {
        su8 vf = *(const su8*)&v_lds[cur][fd * 16 + lr][kk * 32 + lg * 8];
        O[fd] = mfma16(pf, vf, O[fd]);
      }
    }
    __builtin_amdgcn_s_setprio(0);

    if (kb + 1 < nkb) {
      asm volatile("s_waitcnt vmcnt(0)" ::: "memory");
      V_WRITE(nxt);
      asm volatile("" ::: "memory");
    }
    __syncthreads();
  }

  #pragma unroll
  for (int i = 0; i < 4; i++) {
    float inv = 1.f / l_i[i];
    int tq = t0 + w * 16 + lg * 4 + i;
    #pragma unroll
    for (int fd = 0; fd < 8; fd++) {
      size_t off = (size_t)tq * HID + h * HD + fd * 16 + lr;
      if (BF16OUT) ((unsigned short*)ctx)[off] = f2bf(O[fd][i] * inv);
      else ((float*)ctx)[off] = O[fd][i] * inv;
    }
  }
}

// ---------------------------------------------------------------------------
extern "C" void kernel_launch(void* const* d_in, const int* in_sizes, int n_in,
                              void* d_out, int out_size, void* d_ws, size_t ws_size,
                              hipStream_t stream) {
  const float* hidden = (const float*)d_in[0];
  const int* pos = (const int*)d_in[1];
  const int* seq = (const int*)d_in[2];
  const int* vmask = (const int*)d_in[3];
  const int* bo = (const int*)d_in[4];
  const float* kc_in = (const float*)d_in[5];
  const float* vc_in = (const float*)d_in[6];
  const float* wqv = (const float*)d_in[7];
  const float* wql = (const float*)d_in[8];
  const float* wdv = (const float*)d_in[9];
  const float* wdl = (const float*)d_in[10];
  const float* invf = (const float*)d_in[11];
  int max_blocks = in_sizes[4] / 4;

  float* out_attn = (float*)d_out;                 // [2048][4096]
  float* kc_out = out_attn + (size_t)T_TOK * HID;  // [64][64][8][128]
  float* vc_out = kc_out + (size_t)4194304;

  (void)hipMemcpyAsync(kc_out, kc_in, (size_t)4194304 * 4, hipMemcpyDeviceToDevice, stream);
  (void)hipMemcpyAsync(vc_out, vc_in, (size_t)4194304 * 4, hipMemcpyDeviceToDevice, stream);

  char* ws = (char*)d_ws;
  const size_t WT_BYTES   = 100663296;  // 2 x [6144][4096] bf16 (reused for dense)
  const size_t R0_BYTES   = 67108864;   // qkv_bf (25MB) + x_bf (16.8MB); ctx_bf aliases qkv
  const size_t REQ  = WT_BYTES + R0_BYTES + 16777216 /*q*/ + 2 * 4194304 /*k,v*/ + 32768;

  if (ws_size >= REQ) {
    // ---- bf16 fast path ----
    unsigned short* wt0   = (unsigned short*)ws;
    unsigned short* wt_qv = wt0;                       // [6144][4096]
    unsigned short* wt_ql = wt0 + (size_t)25165824;
    unsigned short* wt_dv = wt0;                       // [4096][4096] (after QKV GEMM)
    unsigned short* wt_dl = wt0 + (size_t)16777216;
    unsigned short* qkv_bf = (unsigned short*)(ws + WT_BYTES);   // [2048][6144] bf16
    unsigned short* ctx_bf = qkv_bf;                             // reused after rope
    unsigned short* x_bf  = (unsigned short*)(ws + WT_BYTES + 25165824 * 2);
    unsigned short* q_ws  = (unsigned short*)(ws + WT_BYTES + R0_BYTES);
    unsigned short* k_ws  = q_ws + (size_t)NH * T_TOK * HD;
    unsigned short* v_ws  = k_ws + (size_t)NKV * T_TOK * HD;
    int* idx_v = (int*)(v_ws + (size_t)NKV * T_TOK * HD);
    int* idx_l = idx_v + T_TOK;
    int* cnts  = idx_l + T_TOK;

    route_kernel<<<1, 256, 0, stream>>>(vmask, idx_v, idx_l, cnts);
    convert_wt2<<<dim3(96, 64, 2), 256, 0, stream>>>(wqv, wql, wt_qv, wt_ql, NQKV);
    convert_x<<<4096, 256, 0, stream>>>(hidden, x_bf, T_TOK * HID / 8);
    gemm_bf16<true><<<dim3(NQKV / 128, 16, 2), 256, 0, stream>>>(
        x_bf, wt_qv, wt_ql, idx_v, idx_l, cnts, (void*)qkv_bf, NQKV);
    rope_scatter_bf<<<T_TOK, 256, 0, stream>>>(
        qkv_bf, pos, seq, bo, max_blocks, invf, q_ws, k_ws, v_ws, kc_out, vc_out);
    convert_wt2<<<dim3(64, 64, 2), 256, 0, stream>>>(wdv, wdl, wt_dv, wt_dl, HID);
    attn_kernel<true><<<dim3(T_TOK / 64, NH), 256, 0, stream>>>(
        q_ws, k_ws, v_ws, pos, (void*)ctx_bf);
    gemm_bf16<false><<<dim3(HID / 128, 16, 2), 256, 0, stream>>>(
        ctx_bf, wt_dv, wt_dl, idx_v, idx_l, cnts, (void*)out_attn, HID);
  } else {
    // ---- fallback: round-2 path ----
    float* qkv_ws = (float*)ws;
    float* ctx_ws = (float*)ws;
    size_t off = (size_t)T_TOK * NQKV * 4;
    unsigned short* q_ws = (unsigned short*)(ws + off);
    unsigned short* k_ws = q_ws + (size_t)NH * T_TOK * HD;
    unsigned short* v_ws = k_ws + (size_t)NKV * T_TOK * HD;
    int* idx_v = (int*)(v_ws + (size_t)NKV * T_TOK * HD);
    int* idx_l = idx_v + T_TOK;
    int* cnts = idx_l + T_TOK;

    route_kernel<<<1, 256, 0, stream>>>(vmask, idx_v, idx_l, cnts);
    gemm_gather<<<dim3(NQKV / 64, 16, 2), 256, 0, stream>>>(
        hidden, wqv, wql, idx_v, idx_l, cnts, qkv_ws, NQKV);
    rope_scatter<<<T_TOK, 256, 0, stream>>>(
        qkv_ws, pos, seq, bo, max_blocks, invf, q_ws, k_ws, v_ws, kc_out, vc_out);
    attn_kernel<false><<<dim3(T_TOK / 64, NH), 256, 0, stream>>>(
        q_ws, k_ws, v_ws, pos, (void*)ctx_ws);
    gemm_gather<<<dim3(HID / 64, 16, 2), 256, 0, stream>>>(
        ctx_ws, wdv, wdl, idx_v, idx_l, cnts, out_attn, HID);
  }
}

// Round 14
// 424.765 us; speedup vs baseline: 1.0943x; 1.0943x over previous
//
#include <hip/hip_runtime.h>
#include <hip/hip_bf16.h>
#include <stdint.h>

#define T_TOK 2048
#define HID   4096
#define NH    32
#define NKV   8
#define HD    128
#define NQKV  6144
#define QSCALE 0.08838834764831845f  // 1/sqrt(128)

typedef __bf16 bf16x8 __attribute__((ext_vector_type(8)));
typedef float  f32x4  __attribute__((ext_vector_type(4)));
typedef unsigned short su8 __attribute__((ext_vector_type(8)));
typedef unsigned short su4 __attribute__((ext_vector_type(4)));

__device__ __forceinline__ unsigned short f2bf(float f) {
  union { float f; unsigned u; } x; x.f = f;
  unsigned r = x.u + 0x7FFFu + ((x.u >> 16) & 1u);
  return (unsigned short)(r >> 16);
}
__device__ __forceinline__ float bf2f(unsigned short u) {
  union { unsigned u; float f; } x; x.u = (unsigned)u << 16; return x.f;
}

__device__ __forceinline__ f32x4 mfma16(su8 a, su8 b, f32x4 c) {
  return __builtin_amdgcn_mfma_f32_16x16x32_bf16(
      __builtin_bit_cast(bf16x8, a), __builtin_bit_cast(bf16x8, b), c, 0, 0, 0);
}

#define GLOAD_LDS16(gp, lp)                                                     \
  __builtin_amdgcn_global_load_lds(                                             \
      (const __attribute__((address_space(1))) void*)(gp),                      \
      (__attribute__((address_space(3))) void*)(lp), 16, 0, 0)

// ---------------------------------------------------------------------------
// Routing: compact token indices per expert (vision / language)
// ---------------------------------------------------------------------------
__launch_bounds__(256)
__global__ void route_kernel(const int* __restrict__ vm,
                             int* __restrict__ idx_v, int* __restrict__ idx_l,
                             int* __restrict__ cnts) {
  __shared__ int sv[256], sl[256];
  int tid = threadIdx.x;
  int loc[8]; int lv = 0;
  #pragma unroll
  for (int i = 0; i < 8; i++) { loc[i] = (vm[tid * 8 + i] != 0); lv += loc[i]; }
  int ll = 8 - lv;
  sv[tid] = lv; sl[tid] = ll;
  __syncthreads();
  for (int off = 1; off < 256; off <<= 1) {
    int a = (tid >= off) ? sv[tid - off] : 0;
    int b = (tid >= off) ? sl[tid - off] : 0;
    __syncthreads();
    sv[tid] += a; sl[tid] += b;
    __syncthreads();
  }
  int bv = sv[tid] - lv, bl = sl[tid] - ll;
  #pragma unroll
  for (int i = 0; i < 8; i++) {
    int t = tid * 8 + i;
    if (loc[i]) idx_v[bv++] = t; else idx_l[bl++] = t;
  }
  if (tid == 255) { cnts[0] = sv[255]; cnts[1] = sl[255]; }
}

// ---------------------------------------------------------------------------
// Transpose-convert both experts' weights: W[k][n] f32 -> Wt[n][k] bf16
// ---------------------------------------------------------------------------
__launch_bounds__(256)
__global__ void convert_wt2(const float* __restrict__ W0, const float* __restrict__ W1,
                            unsigned short* __restrict__ Wt0, unsigned short* __restrict__ Wt1,
                            int N) {
  const float* W = blockIdx.z ? W1 : W0;
  unsigned short* Wt = blockIdx.z ? Wt1 : Wt0;
  __shared__ float tile[64][65];
  int n0 = blockIdx.x * 64, k0 = blockIdx.y * 64;
  int tid = threadIdx.x;
  int tr = tid >> 4, tc4 = (tid & 15) * 4;
  #pragma unroll
  for (int p = 0; p < 4; p++) {
    int k = p * 16 + tr;
    float4 v = *(const float4*)(W + (size_t)(k0 + k) * N + n0 + tc4);
    tile[tc4 + 0][k] = v.x; tile[tc4 + 1][k] = v.y;
    tile[tc4 + 2][k] = v.z; tile[tc4 + 3][k] = v.w;
  }
  __syncthreads();
  int n = tid >> 2, kc = (tid & 3) * 16;
  unsigned short obuf[16];
  #pragma unroll
  for (int j = 0; j < 16; j++) obuf[j] = f2bf(tile[n][kc + j]);
  su8* dst = (su8*)(Wt + (size_t)(n0 + n) * 4096 + k0 + kc);
  dst[0] = *(su8*)&obuf[0];
  dst[1] = *(su8*)&obuf[8];
}

// f32 -> bf16 elementwise (8 elems/thread)
__launch_bounds__(256)
__global__ void convert_x(const float* __restrict__ x,
                          unsigned short* __restrict__ xb, int n8) {
  int i = blockIdx.x * 256 + threadIdx.x;
  if (i < n8) {
    float4 a = ((const float4*)x)[i * 2], b = ((const float4*)x)[i * 2 + 1];
    su8 u = { f2bf(a.x), f2bf(a.y), f2bf(a.z), f2bf(a.w),
              f2bf(b.x), f2bf(b.y), f2bf(b.z), f2bf(b.w) };
    ((su8*)xb)[i] = u;
  }
}

// ---------------------------------------------------------------------------
// bf16 gathered GEMM, double-buffered, COUNTED vmcnt, STAGE-under-MFMA
// (the verified r9/r12 structure, best measured 427us):
//   iter t: vmcnt(8); bar; ds_read 16 frags -> regs; lgkm(0); bar;
//           STAGE(buf t&1, t+2); setprio(1); 32 MFMA; setprio(0)
// BM=128 BN=128 BK=64, 4 waves (2x2), wave tile 64x64, LDS 2x32KB = 64KB.
// global_load_lds linear dest + inverse-swizzled global source; reads use
// byte ^= ((row&7)<<4) (G4 recipe) -> 0 bank conflicts (verified r2/r4/r8/r9).
// ---------------------------------------------------------------------------
template <bool OBF16>
__launch_bounds__(256)
__global__ void gemm_bf16(const unsigned short* __restrict__ A,   // [2048][4096]
                          const unsigned short* __restrict__ Wv,  // [N][4096]
                          const unsigned short* __restrict__ Wl,
                          const int* __restrict__ idx_v, const int* __restrict__ idx_l,
                          const int* __restrict__ cnts,
                          void* __restrict__ out, int N) {
  int e = blockIdx.z;
  const unsigned short* Wt = e ? Wl : Wv;
  const int* gidx = e ? idx_l : idx_v;
  int cnt = cnts[e];
  int m0 = blockIdx.y * 128;
  if (cnt == 0 || m0 >= cnt) return;
  // T1: XCD-aware n-tile swizzle (bijective when gridDim.x % 8 == 0)
  int nx = gridDim.x;
  int bx = blockIdx.x;
  int bxs = (nx % 8 == 0) ? ((bx & 7) * (nx >> 3) + (bx >> 3)) : bx;
  int n0 = bxs * 128;

  __shared__ __align__(16) unsigned short a_lds[2][128 * 64];
  __shared__ __align__(16) unsigned short b_lds[2][128 * 64];

  int tid = threadIdx.x;
  int lane = tid & 63;
  int w = tid >> 6;
  int lg = lane >> 4, lr = lane & 15;
  int wm = w >> 1, wn = w & 1;

  // per-lane staging source bases (row = chunk*8 + (lane>>3), swizzled col)
  int srow = lane >> 3;
  int scolb = ((lane & 7) ^ srow) << 4;
  const char* a_src[4];
  const char* b_src[4];
  #pragma unroll
  for (int j = 0; j < 4; j++) {
    int c = w * 4 + j;
    int r = c * 8 + srow;
    int gr = gidx[min(m0 + r, cnt - 1)];
    a_src[j] = (const char*)(A + (size_t)gr * 4096) + scolb;
    b_src[j] = (const char*)(Wt + (size_t)(n0 + r) * 4096) + scolb;
  }

  f32x4 acc[4][4];
  #pragma unroll
  for (int fm = 0; fm < 4; fm++)
    #pragma unroll
    for (int fn = 0; fn < 4; fn++)
      acc[fm][fn] = (f32x4){0.f, 0.f, 0.f, 0.f};

  auto STAGE = [&](int buf, int kt) {
    size_t kb = (size_t)kt * 128;  // 64 k-elems * 2B
    #pragma unroll
    for (int j = 0; j < 4; j++) {
      int c = w * 4 + j;
      GLOAD_LDS16(a_src[j] + kb, (char*)a_lds[buf] + c * 1024);
      GLOAD_LDS16(b_src[j] + kb, (char*)b_lds[buf] + c * 1024);
    }
  };

  // prologue: two tiles in flight
  STAGE(0, 0);
  STAGE(1, 1);

  for (int t = 0; t < 64; ++t) {
    if (t < 63) { asm volatile("s_waitcnt vmcnt(8)" ::: "memory"); }
    else        { asm volatile("s_waitcnt vmcnt(0)" ::: "memory"); }
    __builtin_amdgcn_s_barrier();
    asm volatile("" ::: "memory");

    // ds_read ALL fragments of buf[t&1] into registers
    const char* la = (const char*)a_lds[t & 1];
    const char* lb = (const char*)b_lds[t & 1];
    su8 af[2][4], bfr[2][4];
    #pragma unroll
    for (int s = 0; s < 2; s++) {
      int colb = s * 64 + lg * 16;
      #pragma unroll
      for (int fm = 0; fm < 4; fm++) {
        int r = wm * 64 + fm * 16 + lr;
        af[s][fm] = *(const su8*)(la + r * 128 + (colb ^ ((r & 7) << 4)));
      }
      #pragma unroll
      for (int fn = 0; fn < 4; fn++) {
        int r = wn * 64 + fn * 16 + lr;
        bfr[s][fn] = *(const su8*)(lb + r * 128 + (colb ^ ((r & 7) << 4)));
      }
    }
    // this wave's LDS reads complete, then block-wide barrier -> buf is free
    asm volatile("s_waitcnt lgkmcnt(0)" ::: "memory");
    __builtin_amdgcn_sched_barrier(0);
    __builtin_amdgcn_s_barrier();
    asm volatile("" ::: "memory");

    // issue next-next tile's loads into the just-freed buffer, then MFMA
    if (t + 2 < 64) STAGE(t & 1, t + 2);
    __builtin_amdgcn_s_setprio(1);
    #pragma unroll
    for (int s = 0; s < 2; s++)
      #pragma unroll
      for (int fm = 0; fm < 4; fm++)
        #pragma unroll
        for (int fn = 0; fn < 4; fn++)
          acc[fm][fn] = mfma16(af[s][fm], bfr[s][fn], acc[fm][fn]);
    __builtin_amdgcn_s_setprio(0);
  }

  // epilogue: C/D layout row=(lane>>4)*4+i, col=lane&15
  #pragma unroll
  for (int fm = 0; fm < 4; fm++) {
    #pragma unroll
    for (int i = 0; i < 4; i++) {
      int r = wm * 64 + fm * 16 + lg * 4 + i;
      if (m0 + r < cnt) {
        int grow = gidx[m0 + r];
        #pragma unroll
        for (int fn = 0; fn < 4; fn++) {
          size_t off = (size_t)grow * N + n0 + wn * 64 + fn * 16 + lr;
          if (OBF16) ((unsigned short*)out)[off] = f2bf(acc[fm][fn][i]);
          else       ((float*)out)[off] = acc[fm][fn][i];
        }
      }
    }
  }
}

// ---------------------------------------------------------------------------
// OLD f32-staging gathered GEMM (fallback if workspace is small)
// ---------------------------------------------------------------------------
__launch_bounds__(256)
__global__ void gemm_gather(const float* __restrict__ X,
                            const float* __restrict__ Wv, const float* __restrict__ Wl,
                            const int* __restrict__ idx_v, const int* __restrict__ idx_l,
                            const int* __restrict__ cnts,
                            float* __restrict__ out, int N) {
  int e = blockIdx.z;
  const float* W = e ? Wl : Wv;
  const int* gidx = e ? idx_l : idx_v;
  int cnt = cnts[e];
  int m0 = blockIdx.y * 128;
  if (cnt == 0 || m0 >= cnt) return;
  int n0 = blockIdx.x * 64;

  __shared__ __align__(16) unsigned short a_lds[128][72];
  __shared__ __align__(16) unsigned short b_lds[64][72];

  int tid = threadIdx.x;
  int lane = tid & 63;
  int w = tid >> 6;
  int lg = lane >> 4, lr = lane & 15;
  int wm = w >> 1, wn = w & 1;

  int ar = tid >> 1;
  int akc = (tid & 1) * 32;
  const float* Arow = X + (size_t)gidx[min(m0 + ar, cnt - 1)] * HID;
  int bk = (tid >> 4) * 4;
  int bj = (tid & 15) * 4;

  f32x4 acc[4][2];
  #pragma unroll
  for (int fm = 0; fm < 4; fm++)
    #pragma unroll
    for (int fn = 0; fn < 2; fn++)
      acc[fm][fn] = (f32x4){0.f, 0.f, 0.f, 0.f};

  for (int k0 = 0; k0 < HID; k0 += 64) {
    {
      const float4* src = (const float4*)(Arow + k0 + akc);
      float4 f[8];
      #pragma unroll
      for (int i = 0; i < 8; i++) f[i] = src[i];
      #pragma unroll
      for (int i = 0; i < 4; i++) {
        float4 a0 = f[2 * i], a1 = f[2 * i + 1];
        su8 u = { f2bf(a0.x), f2bf(a0.y), f2bf(a0.z), f2bf(a0.w),
                  f2bf(a1.x), f2bf(a1.y), f2bf(a1.z), f2bf(a1.w) };
        *(su8*)&a_lds[ar][akc + i * 8] = u;
      }
    }
    {
      const float* Wp = W + (size_t)(k0 + bk) * N + n0 + bj;
      float4 r0 = *(const float4*)(Wp);
      float4 r1 = *(const float4*)(Wp + N);
      float4 r2 = *(const float4*)(Wp + 2 * (size_t)N);
      float4 r3 = *(const float4*)(Wp + 3 * (size_t)N);
      su4 c0 = { f2bf(r0.x), f2bf(r1.x), f2bf(r2.x), f2bf(r3.x) };
      su4 c1 = { f2bf(r0.y), f2bf(r1.y), f2bf(r2.y), f2bf(r3.y) };
      su4 c2 = { f2bf(r0.z), f2bf(r1.z), f2bf(r2.z), f2bf(r3.z) };
      su4 c3 = { f2bf(r0.w), f2bf(r1.w), f2bf(r2.w), f2bf(r3.w) };
      *(su4*)&b_lds[bj + 0][bk] = c0;
      *(su4*)&b_lds[bj + 1][bk] = c1;
      *(su4*)&b_lds[bj + 2][bk] = c2;
      *(su4*)&b_lds[bj + 3][bk] = c3;
    }
    __syncthreads();
    #pragma unroll
    for (int s = 0; s < 64; s += 32) {
      su8 af[4], bfr[2];
      #pragma unroll
      for (int fm = 0; fm < 4; fm++)
        af[fm] = *(const su8*)&a_lds[wm * 64 + fm * 16 + lr][s + lg * 8];
      #pragma unroll
      for (int fn = 0; fn < 2; fn++)
        bfr[fn] = *(const su8*)&b_lds[wn * 32 + fn * 16 + lr][s + lg * 8];
      #pragma unroll
      for (int fm = 0; fm < 4; fm++)
        #pragma unroll
        for (int fn = 0; fn < 2; fn++)
          acc[fm][fn] = mfma16(af[fm], bfr[fn], acc[fm][fn]);
    }
    __syncthreads();
  }
  #pragma unroll
  for (int fm = 0; fm < 4; fm++) {
    #pragma unroll
    for (int i = 0; i < 4; i++) {
      int r = wm * 64 + fm * 16 + lg * 4 + i;
      if (m0 + r < cnt) {
        int grow = gidx[m0 + r];
        #pragma unroll
        for (int fn = 0; fn < 2; fn++)
          out[(size_t)grow * N + n0 + wn * 32 + fn * 16 + lr] = acc[fm][fn][i];
      }
    }
  }
}

// ---------------------------------------------------------------------------
// RoPE + cache scatter (bf16 qkv input, vectorized)
// ---------------------------------------------------------------------------
__launch_bounds__(256)
__global__ void rope_scatter_bf(const unsigned short* __restrict__ qkv,
                                const int* __restrict__ pos_ids,
                                const int* __restrict__ seq_ids,
                                const int* __restrict__ block_offsets, int max_blocks,
                                const float* __restrict__ inv_freq,
                                unsigned short* __restrict__ q_ws,
                                unsigned short* __restrict__ k_ws,
                                unsigned short* __restrict__ v_ws,
                                float* __restrict__ kc_out, float* __restrict__ vc_out) {
  int t = blockIdx.x;
  int tid = threadIdx.x;
  __shared__ float cs[64], sn[64];
  int pos = pos_ids[t];
  if (tid < 64) {
    float f = (float)pos * inv_freq[tid];
    float s, c;
    sincosf(f, &s, &c);
    cs[tid] = c; sn[tid] = s;
  }
  __syncthreads();
  const unsigned short* row = qkv + (size_t)t * NQKV;
  #pragma unroll
  for (int it = 0; it < 2; it++) {
    int chunk = it * 256 + tid;
    int hh = chunk >> 4;
    int d0 = (chunk & 15) * 8;
    int lo = (d0 < 64);
    int j0 = lo ? d0 : d0 - 64;
    su8 x  = *(const su8*)(row + hh * 128 + d0);
    su8 xp = *(const su8*)(row + hh * 128 + (lo ? d0 + 64 : d0 - 64));
    su8 o;
    #pragma unroll
    for (int jj = 0; jj < 8; jj++) {
      float c = cs[j0 + jj], s = sn[j0 + jj];
      float xv = bf2f(x[jj]), pv = bf2f(xp[jj]);
      float val = lo ? (xv * c - pv * s) : (xv * c + pv * s);
      o[jj] = f2bf(val * QSCALE);
    }
    *(su8*)(q_ws + ((size_t)hh * T_TOK + t) * HD + d0) = o;
  }
  int seq = seq_ids[t];
  int blk = block_offsets[seq * max_blocks + (pos >> 6)];
  int slot = pos & 63;
  int chunk = tid & 127;
  int kvh = chunk >> 4;
  int d0 = (chunk & 15) * 8;
  if (tid < 128) {
    const unsigned short* kr = row + HID;
    int lo = (d0 < 64);
    int j0 = lo ? d0 : d0 - 64;
    su8 x  = *(const su8*)(kr + kvh * 128 + d0);
    su8 xp = *(const su8*)(kr + kvh * 128 + (lo ? d0 + 64 : d0 - 64));
    su8 o;
    float of[8];
    #pragma unroll
    for (int jj = 0; jj < 8; jj++) {
      float c = cs[j0 + jj], s = sn[j0 + jj];
      float xv = bf2f(x[jj]), pv = bf2f(xp[jj]);
      float val = lo ? (xv * c - pv * s) : (xv * c + pv * s);
      of[jj] = val;
      o[jj] = f2bf(val);
    }
    *(su8*)(k_ws + ((size_t)kvh * T_TOK + t) * HD + d0) = o;
    float* kc = kc_out + (((size_t)blk * 64 + slot) * NKV + kvh) * HD + d0;
    *(float4*)kc       = (float4){of[0], of[1], of[2], of[3]};
    *(float4*)(kc + 4) = (float4){of[4], of[5], of[6], of[7]};
  } else {
    const unsigned short* vr = row + HID + NKV * HD;
    su8 x = *(const su8*)(vr + kvh * 128 + d0);
    *(su8*)(v_ws + ((size_t)kvh * T_TOK + t) * HD + d0) = x;
    float* vc = vc_out + (((size_t)blk * 64 + slot) * NKV + kvh) * HD + d0;
    *(float4*)vc       = (float4){bf2f(x[0]), bf2f(x[1]), bf2f(x[2]), bf2f(x[3])};
    *(float4*)(vc + 4) = (float4){bf2f(x[4]), bf2f(x[5]), bf2f(x[6]), bf2f(x[7])};
  }
}

// ---------------------------------------------------------------------------
// RoPE + cache scatter (f32 qkv input, fallback path)
// ---------------------------------------------------------------------------
__launch_bounds__(256)
__global__ void rope_scatter(const float* __restrict__ qkv,
                             const int* __restrict__ pos_ids,
                             const int* __restrict__ seq_ids,
                             const int* __restrict__ block_offsets, int max_blocks,
                             const float* __restrict__ inv_freq,
                             unsigned short* __restrict__ q_ws,
                             unsigned short* __restrict__ k_ws,
                             unsigned short* __restrict__ v_ws,
                             float* __restrict__ kc_out, float* __restrict__ vc_out) {
  int t = blockIdx.x;
  int tid = threadIdx.x;
  __shared__ float cs[64], sn[64];
  int pos = pos_ids[t];
  if (tid < 64) {
    float f = (float)pos * inv_freq[tid];
    float s, c;
    sincosf(f, &s, &c);
    cs[tid] = c; sn[tid] = s;
  }
  __syncthreads();
  const float* row = qkv + (size_t)t * NQKV;
  #pragma unroll 4
  for (int it = 0; it < 16; it++) {
    int idx = it * 256 + tid;
    int hh = idx >> 7, d = idx & 127;
    float val;
    if (d < 64) val = row[hh * 128 + d] * cs[d] - row[hh * 128 + d + 64] * sn[d];
    else { int j = d - 64; val = row[hh * 128 + d] * cs[j] + row[hh * 128 + j] * sn[j]; }
    q_ws[((size_t)hh * T_TOK + t) * HD + d] = f2bf(val * QSCALE);
  }
  int seq = seq_ids[t];
  int blk = block_offsets[seq * max_blocks + (pos >> 6)];
  int slot = pos & 63;
  #pragma unroll
  for (int it = 0; it < 4; it++) {
    int idx = it * 256 + tid;
    int kvh = idx >> 7, d = idx & 127;
    const float* kr = row + HID;
    float val;
    if (d < 64) val = kr[kvh * 128 + d] * cs[d] - kr[kvh * 128 + d + 64] * sn[d];
    else { int j = d - 64; val = kr[kvh * 128 + d] * cs[j] + kr[kvh * 128 + j] * sn[j]; }
    kc_out[(((size_t)blk * 64 + slot) * NKV + kvh) * HD + d] = val;
    k_ws[((size_t)kvh * T_TOK + t) * HD + d] = f2bf(val);
  }
  #pragma unroll
  for (int it = 0; it < 4; it++) {
    int idx = it * 256 + tid;
    int kvh = idx >> 7, d = idx & 127;
    float val = row[HID + NKV * HD + idx];
    vc_out[(((size_t)blk * 64 + slot) * NKV + kvh) * HD + d] = val;
    v_ws[((size_t)kvh * T_TOK + t) * HD + d] = f2bf(val);
  }
}

// ---------------------------------------------------------------------------
// Flash attention, K/V double-buffered pipeline (r12, verified):
//   iter kb: issue K-dma(kb+1) + V-reg-loads(kb+1); compute(kb);
//            vmcnt(0); ds_write V(kb+1); barrier
// ---------------------------------------------------------------------------
template <bool BF16OUT>
__launch_bounds__(256)
__global__ void attn_kernel(const unsigned short* __restrict__ q_ws,
                            const unsigned short* __restrict__ k_ws,
                            const unsigned short* __restrict__ v_ws,
                            const int* __restrict__ pos_ids,
                            void* __restrict__ ctx) {
  int qt = blockIdx.x;
  int h = blockIdx.y;
  int kvh = h >> 2;
  int t0 = qt * 64;

  __shared__ __align__(16) unsigned short k_lds[2][64 * 128];
  __shared__ __align__(16) unsigned short v_lds[2][128][72];
  __shared__ __align__(16) unsigned short p_lds[4][16][72];
  unsigned short* q_lds = &v_lds[1][0][0];

  int tid = threadIdx.x;
  int lane = tid & 63;
  int w = tid >> 6;
  int lg = lane >> 4, lr = lane & 15;

  int seq_start = t0 - pos_ids[t0];
  int nkb = (t0 - seq_start) / 64 + 1;

  const char* kbase = (const char*)(k_ws + (size_t)kvh * T_TOK * HD);
  int ksrc_off[4];
  #pragma unroll
  for (int j = 0; j < 4; j++) {
    int c = w * 4 + j;
    int r = c * 4 + (lane >> 4);
    ksrc_off[j] = r * 256 + (((lane & 15) ^ (r & 7)) << 4);
  }
  auto K_STAGE = [&](int buf, int kt0) {
    const char* src = kbase + (size_t)kt0 * 256;
    #pragma unroll
    for (int j = 0; j < 4; j++) {
      int c = w * 4 + j;
      GLOAD_LDS16(src + ksrc_off[j], (char*)k_lds[buf] + c * 1024 + (lane & 63) * 16);
    }
  };
  int vd0 = (tid & 31) * 4, vkey0 = (tid >> 5) * 8;
  su4 vv[8];
  auto V_LOAD = [&](int kt0) {
    #pragma unroll
    for (int r = 0; r < 8; r++)
      vv[r] = *(const su4*)(v_ws + ((size_t)kvh * T_TOK + kt0 + vkey0 + r) * HD + vd0);
  };
  auto V_WRITE = [&](int buf) {
    #pragma unroll
    for (int dd = 0; dd < 4; dd++) {
      su8 u = { vv[0][dd], vv[1][dd], vv[2][dd], vv[3][dd],
                vv[4][dd], vv[5][dd], vv[6][dd], vv[7][dd] };
      *(su8*)&v_lds[buf][vd0 + dd][vkey0] = u;
    }
  };

  {
    int r = tid >> 2, dc = (tid & 3) * 32;
    const su8* src = (const su8*)(q_ws + ((size_t)h * T_TOK + t0 + r) * HD + dc);
    #pragma unroll
    for (int i = 0; i < 4; i++) *(su8*)&q_lds[r * 136 + dc + i * 8] = src[i];
  }
  K_STAGE(0, seq_start);
  V_LOAD(seq_start);
  __syncthreads();
  su8 qf[4];
  #pragma unroll
  for (int s = 0; s < 4; s++)
    qf[s] = *(const su8*)&q_lds[(w * 16 + lr) * 136 + s * 32 + lg * 8];
  asm volatile("s_waitcnt lgkmcnt(0)" ::: "memory");
  __builtin_amdgcn_sched_barrier(0);
  __builtin_amdgcn_s_barrier();
  asm volatile("s_waitcnt vmcnt(0)" ::: "memory");
  V_WRITE(0);
  asm volatile("" ::: "memory");
  __syncthreads();

  f32x4 O[8];
  #pragma unroll
  for (int fd = 0; fd < 8; fd++) O[fd] = (f32x4){0.f, 0.f, 0.f, 0.f};
  float m_i[4] = { -1e30f, -1e30f, -1e30f, -1e30f };
  float l_i[4] = { 0.f, 0.f, 0.f, 0.f };

  for (int kb = 0; kb < nkb; kb++) {
    int cur = kb & 1, nxt = cur ^ 1;
    int kt0 = seq_start + kb * 64;
    if (kb + 1 < nkb) {
      K_STAGE(nxt, kt0 + 64);
      V_LOAD(kt0 + 64);
    }

    const char* kl = (const char*)k_lds[cur];
    f32x4 S[4];
    #pragma unroll
    for (int f = 0; f < 4; f++) S[f] = (f32x4){0.f, 0.f, 0.f, 0.f};
    __builtin_amdgcn_s_setprio(1);
    #pragma unroll
    for (int f = 0; f < 4; f++) {
      int r = f * 16 + lr;
      #pragma unroll
      for (int s = 0; s < 4; s++) {
        su8 kf = *(const su8*)(kl + r * 256 + ((s * 64 + lg * 16) ^ ((r & 7) << 4)));
        S[f] = mfma16(qf[s], kf, S[f]);
      }
    }
    __builtin_amdgcn_s_setprio(0);
    if (kt0 == t0) {
      #pragma unroll
      for (int f = 0; f < 4; f++)
        #pragma unroll
        for (int i = 0; i < 4; i++)
          if (f * 16 + lr > w * 16 + lg * 4 + i) S[f][i] = -1e30f;
    }
    float mnew[4], alpha[4];
    #pragma unroll
    for (int i = 0; i < 4; i++) {
      float mx = fmaxf(fmaxf(S[0][i], S[1][i]), fmaxf(S[2][i], S[3][i]));
      #pragma unroll
      for (int off = 8; off > 0; off >>= 1) mx = fmaxf(mx, __shfl_xor(mx, off, 16));
      mnew[i] = fmaxf(m_i[i], mx);
      alpha[i] = __expf(m_i[i] - mnew[i]);
      m_i[i] = mnew[i];
    }
    float rs[4] = { 0.f, 0.f, 0.f, 0.f };
    #pragma unroll
    for (int f = 0; f < 4; f++)
      #pragma unroll
      for (int i = 0; i < 4; i++) {
        float p = __expf(S[f][i] - mnew[i]);
        S[f][i] = p;
        rs[i] += p;
      }
    #pragma unroll
    for (int i = 0; i < 4; i++) {
      #pragma unroll
      for (int off = 8; off > 0; off >>= 1) rs[i] += __shfl_xor(rs[i], off, 16);
      l_i[i] = l_i[i] * alpha[i] + rs[i];
    }
    #pragma unroll
    for (int f = 0; f < 4; f++)
      #pragma unroll
      for (int i = 0; i < 4; i++)
        p_lds[w][lg * 4 + i][f * 16 + lr] = f2bf(S[f][i]);
    #pragma unroll
    for (int fd = 0; fd < 8; fd++)
      #pragma unroll
      for (int i = 0; i < 4; i++)
        O[fd][i] *= alpha[i];
    __builtin_amdgcn_s_setprio(1);
    #pragma unroll
    for (int kk = 0; kk < 2; kk++) {
      su8 pf = *(const su8*)&p_lds[w][lr][kk * 32 + lg * 8];
      #pragma unroll
      for (int fd = 0; fd < 8; fd++) {
        su8 vf = *(const su8*)&v_lds[cur][fd * 16 + lr][kk * 32 + lg * 8];
        O[fd] = mfma16(pf, vf, O[fd]);
      }
    }
    __builtin_amdgcn_s_setprio(0);

    if (kb + 1 < nkb) {
      asm volatile("s_waitcnt vmcnt(0)" ::: "memory");
      V_WRITE(nxt);
      asm volatile("" ::: "memory");
    }
    __syncthreads();
  }

  #pragma unroll
  for (int i = 0; i < 4; i++) {
    float inv = 1.f / l_i[i];
    int tq = t0 + w * 16 + lg * 4 + i;
    #pragma unroll
    for (int fd = 0; fd < 8; fd++) {
      size_t off = (size_t)tq * HID + h * HD + fd * 16 + lr;
      if (BF16OUT) ((unsigned short*)ctx)[off] = f2bf(O[fd][i] * inv);
      else ((float*)ctx)[off] = O[fd][i] * inv;
    }
  }
}

// ---------------------------------------------------------------------------
extern "C" void kernel_launch(void* const* d_in, const int* in_sizes, int n_in,
                              void* d_out, int out_size, void* d_ws, size_t ws_size,
                              hipStream_t stream) {
  const float* hidden = (const float*)d_in[0];
  const int* pos = (const int*)d_in[1];
  const int* seq = (const int*)d_in[2];
  const int* vmask = (const int*)d_in[3];
  const int* bo = (const int*)d_in[4];
  const float* kc_in = (const float*)d_in[5];
  const float* vc_in = (const float*)d_in[6];
  const float* wqv = (const float*)d_in[7];
  const float* wql = (const float*)d_in[8];
  const float* wdv = (const float*)d_in[9];
  const float* wdl = (const float*)d_in[10];
  const float* invf = (const float*)d_in[11];
  int max_blocks = in_sizes[4] / 4;

  float* out_attn = (float*)d_out;                 // [2048][4096]
  float* kc_out = out_attn + (size_t)T_TOK * HID;  // [64][64][8][128]
  float* vc_out = kc_out + (size_t)4194304;

  (void)hipMemcpyAsync(kc_out, kc_in, (size_t)4194304 * 4, hipMemcpyDeviceToDevice, stream);
  (void)hipMemcpyAsync(vc_out, vc_in, (size_t)4194304 * 4, hipMemcpyDeviceToDevice, stream);

  char* ws = (char*)d_ws;
  const size_t WT_BYTES   = 100663296;  // 2 x [6144][4096] bf16 (reused for dense)
  const size_t R0_BYTES   = 67108864;   // qkv_bf (25MB) + x_bf (16.8MB); ctx_bf aliases qkv
  const size_t REQ  = WT_BYTES + R0_BYTES + 16777216 /*q*/ + 2 * 4194304 /*k,v*/ + 32768;

  if (ws_size >= REQ) {
    // ---- bf16 fast path ----
    unsigned short* wt0   = (unsigned short*)ws;
    unsigned short* wt_qv = wt0;                       // [6144][4096]
    unsigned short* wt_ql = wt0 + (size_t)25165824;
    unsigned short* wt_dv = wt0;                       // [4096][4096] (after QKV GEMM)
    unsigned short* wt_dl = wt0 + (size_t)16777216;
    unsigned short* qkv_bf = (unsigned short*)(ws + WT_BYTES);   // [2048][6144] bf16
    unsigned short* ctx_bf = qkv_bf;                             // reused after rope
    unsigned short* x_bf  = (unsigned short*)(ws + WT_BYTES + 25165824 * 2);
    unsigned short* q_ws  = (unsigned short*)(ws + WT_BYTES + R0_BYTES);
    unsigned short* k_ws  = q_ws + (size_t)NH * T_TOK * HD;
    unsigned short* v_ws  = k_ws + (size_t)NKV * T_TOK * HD;
    int* idx_v = (int*)(v_ws + (size_t)NKV * T_TOK * HD);
    int* idx_l = idx_v + T_TOK;
    int* cnts  = idx_l + T_TOK;

    route_kernel<<<1, 256, 0, stream>>>(vmask, idx_v, idx_l, cnts);
    convert_wt2<<<dim3(96, 64, 2), 256, 0, stream>>>(wqv, wql, wt_qv, wt_ql, NQKV);
    convert_x<<<4096, 256, 0, stream>>>(hidden, x_bf, T_TOK * HID / 8);
    gemm_bf16<true><<<dim3(NQKV / 128, 16, 2), 256, 0, stream>>>(
        x_bf, wt_qv, wt_ql, idx_v, idx_l, cnts, (void*)qkv_bf, NQKV);
    rope_scatter_bf<<<T_TOK, 256, 0, stream>>>(
        qkv_bf, pos, seq, bo, max_blocks, invf, q_ws, k_ws, v_ws, kc_out, vc_out);
    convert_wt2<<<dim3(64, 64, 2), 256, 0, stream>>>(wdv, wdl, wt_dv, wt_dl, HID);
    attn_kernel<true><<<dim3(T_TOK / 64, NH), 256, 0, stream>>>(
        q_ws, k_ws, v_ws, pos, (void*)ctx_bf);
    gemm_bf16<false><<<dim3(HID / 128, 16, 2), 256, 0, stream>>>(
        ctx_bf, wt_dv, wt_dl, idx_v, idx_l, cnts, (void*)out_attn, HID);
  } else {
    // ---- fallback: round-2 path ----
    float* qkv_ws = (float*)ws;
    float* ctx_ws = (float*)ws;
    size_t off = (size_t)T_TOK * NQKV * 4;
    unsigned short* q_ws = (unsigned short*)(ws + off);
    unsigned short* k_ws = q_ws + (size_t)NH * T_TOK * HD;
    unsigned short* v_ws = k_ws + (size_t)NKV * T_TOK * HD;
    int* idx_v = (int*)(v_ws + (size_t)NKV * T_TOK * HD);
    int* idx_l = idx_v + T_TOK;
    int* cnts = idx_l + T_TOK;

    route_kernel<<<1, 256, 0, stream>>>(vmask, idx_v, idx_l, cnts);
    gemm_gather<<<dim3(NQKV / 64, 16, 2), 256, 0, stream>>>(
        hidden, wqv, wql, idx_v, idx_l, cnts, qkv_ws, NQKV);
    rope_scatter<<<T_TOK, 256, 0, stream>>>(
        qkv_ws, pos, seq, bo, max_blocks, invf, q_ws, k_ws, v_ws, kc_out, vc_out);
    attn_kernel<false><<<dim3(T_TOK / 64, NH), 256, 0, stream>>>(
        q_ws, k_ws, v_ws, pos, (void*)ctx_ws);
    gemm_gather<<<dim3(HID / 64, 16, 2), 256, 0, stream>>>(
        ctx_ws, wdv, wdl, idx_v, idx_l, cnts, out_attn, HID);
  }
}